// Round 9
// baseline (149.604 us; speedup 1.0000x reference)
//
#include <hip/hip_runtime.h>
#include <hip/hip_bf16.h>

// MSA: B=2, S=4096, D=256, H=4, DH=64. fp32 in/out, bf16 MFMA internally.
// R9: T15 two-tile in-wave pipeline on R4's proven skeleton.
//     Separate score regs sA/sB break the WAR hazard so qkt(t+1) MFMAs
//     issue BEFORE smpv(t) VALU and drain under it. 2 LDS buffers,
//     1 barrier/tile (R4 scheme). K buf t&1: last read qkt(t), 1 barrier
//     back. V buf (t+1)&1: last read smpv(t-1), 1 barrier back. Extra
//     barrier after preloop qkt(0) protects first kwrite.

#define B_   2
#define S_   4096
#define D_   256
#define H_   4
#define DH_  64
#define BH_  8
#define NTOK (BH_*S_*DH_)   // elements per Q/K/V buffer

#define KVB  64             // kv tile per step
#define QW   32             // q rows per wave
#define NW   8              // waves per block
#define QB   (QW*NW)        // 256 q rows per block
#define NINST (BH_*(S_/QW)) // 1024 q-wave instances

typedef short v8s __attribute__((ext_vector_type(8)));
typedef float v16f __attribute__((ext_vector_type(16)));
typedef float v4f __attribute__((ext_vector_type(4)));
typedef unsigned v4u __attribute__((ext_vector_type(4)));
typedef unsigned v2u __attribute__((ext_vector_type(2)));
typedef int v2i __attribute__((ext_vector_type(2)));

#define QSCL (0.125f * 1.4426950408889634f)   // 1/sqrt(64) * log2(e): exp2 domain
#define DEFER_THR 8.0f                        // T13: P bounded by 2^8

static __device__ __forceinline__ short f2bf(float f) {
    __hip_bfloat16 h = __float2bfloat16(f);
    return *reinterpret_cast<short*>(&h);
}
static __device__ __forceinline__ unsigned cvtpk(float lo, float hi) {
    unsigned r;
    asm("v_cvt_pk_bf16_f32 %0, %1, %2" : "=v"(r) : "v"(lo), "v"(hi));
    return r;
}
// Raw v_exp_f32: args are <=0 finite; denormal flush acceptable here.
static __device__ __forceinline__ float fexp2(float x) {
#if __has_builtin(__builtin_amdgcn_exp2f)
    return __builtin_amdgcn_exp2f(x);
#else
    float r;
    asm("v_exp_f32 %0, %1" : "=v"(r) : "v"(x));
    return r;
#endif
}
static __device__ __forceinline__ float max3f(float a, float b, float c) {
    return fmaxf(fmaxf(a, b), c);   // clang fuses to v_max3_f32
}
// a' = [a_lo, b_lo]; b' = [a_hi, b_hi]  (v_permlane32_swap_b32)
static __device__ __forceinline__ void pl32swap(unsigned &a, unsigned &b) {
#if __has_builtin(__builtin_amdgcn_permlane32_swap)
    v2i r = __builtin_amdgcn_permlane32_swap((int)a, (int)b, false, false);
    a = (unsigned)r[0]; b = (unsigned)r[1];
#else
    asm volatile("v_permlane32_swap_b32 %0, %1" : "+v"(a), "+v"(b));
#endif
}
// cross-half (lane i <-> i+32) reduce via permlane self-swap
static __device__ __forceinline__ float xmax32(float x) {
    unsigned a = __builtin_bit_cast(unsigned, x), b = a;
    pl32swap(a, b);
    return fmaxf(__builtin_bit_cast(float, a), __builtin_bit_cast(float, b));
}
static __device__ __forceinline__ float xadd32(float x) {
    unsigned a = __builtin_bit_cast(unsigned, x), b = a;
    pl32swap(a, b);
    return __builtin_bit_cast(float, a) + __builtin_bit_cast(float, b);
}
static __device__ __forceinline__ v16f vz16() {
    v16f z;
    #pragma unroll
    for (int i = 0; i < 16; ++i) z[i] = 0.f;
    return z;
}
static __device__ __forceinline__ v8s cvt8(const float* p) {
    v4f f0 = *(const v4f*)(p);
    v4f f1 = *(const v4f*)(p + 4);
    v4u u = { cvtpk(f0[0], f0[1]), cvtpk(f0[2], f0[3]),
              cvtpk(f1[0], f1[1]), cvtpk(f1[2], f1[3]) };
    return __builtin_bit_cast(v8s, u);
}

// ---------------------------------------------------------------------------
// Kernel 1: MFMA QKV projection. Block = 128 thr (2 waves), grid (128, BH).
//   Q: [BH][S][DH] pre-scaled by QSCL; K: [BH][S][DH]; Vt: [BH][DH][S].
// ---------------------------------------------------------------------------
__global__ __launch_bounds__(128) void qkv_proj_mfma(
    const float* __restrict__ x,
    const float* __restrict__ qw, const float* __restrict__ qb,
    const float* __restrict__ kw, const float* __restrict__ kb,
    const float* __restrict__ vw, const float* __restrict__ vb,
    short* __restrict__ Qo, short* __restrict__ Ko, short* __restrict__ Vt)
{
    const int t   = threadIdx.x;
    const int w   = t >> 6;
    const int l   = t & 63;
    const int l31 = l & 31, lhi = l >> 5;
    const int bh  = blockIdx.y, h = bh & 3, b = bh >> 2;
    const int s0  = blockIdx.x * 32;

    // A-frags from X (fp32 -> bf16): A[row=l31][k = k0*16 + lhi*8 + j]
    const float* xrow = x + ((size_t)(b*S_ + s0 + l31))*D_ + h*DH_;
    v8s af[4];
    #pragma unroll
    for (int k0 = 0; k0 < 4; ++k0)
        af[k0] = cvt8(xrow + k0*16 + lhi*8);

    const float* Wp[3] = { qw + h*DH_*DH_, kw + h*DH_*DH_, vw + h*DH_*DH_ };
    const float* Bp[3] = { qb + h*DH_,     kb + h*DH_,     vb + h*DH_ };
    short* Qh = Qo + (size_t)bh*S_*DH_;
    short* Kh = Ko + (size_t)bh*S_*DH_;

    #pragma unroll
    for (int ui = 0; ui < 3; ++ui) {
        const int u  = w*3 + ui;
        const int p  = u >> 1;
        const int eb = u & 1;
        const int e  = eb*32 + l31;
        const float* wrow = Wp[p] + e*DH_;     // W[e][d] row-major

        v16f acc = vz16();
        #pragma unroll
        for (int k0 = 0; k0 < 4; ++k0) {
            v8s bfr = cvt8(wrow + k0*16 + lhi*8);  // B[col=e][k]
            acc = __builtin_amdgcn_mfma_f32_32x32x16_bf16(af[k0], bfr, acc, 0, 0, 0);
        }

        const float bias = Bp[p][e];
        if (p == 0) {
            const float bq = bias * QSCL;
            #pragma unroll
            for (int r = 0; r < 16; ++r) acc[r] = fmaf(acc[r], QSCL, bq);
        } else {
            #pragma unroll
            for (int r = 0; r < 16; ++r) acc[r] += bias;
        }

        if (p < 2) {
            short* dst = (p == 0) ? Qh : Kh;
            #pragma unroll
            for (int r = 0; r < 16; ++r) {
                int s = s0 + (r & 3) + 8*(r >> 2) + 4*lhi;
                dst[(size_t)s*DH_ + e] = f2bf(acc[r]);
            }
        } else {
            short* vtb = Vt + (size_t)bh*DH_*S_ + (size_t)e*S_;
            #pragma unroll
            for (int rq = 0; rq < 4; ++rq) {
                v2u pr = { cvtpk(acc[rq*4+0], acc[rq*4+1]),
                           cvtpk(acc[rq*4+2], acc[rq*4+3]) };
                int s = s0 + rq*8 + 4*lhi;           // 4 consecutive s
                *(v2u*)(vtb + s) = pr;
            }
        }
    }
}

// ---------------------------------------------------------------------------
// Kernel 2: flash attention, swapped QK^T, 32x32x16 MFMA, T15 2-tile pipe.
// Fragment layouts (32x32x16, m74/m101):
//   A: row=lane&31, k=(lane>>5)*8+j ; B: col=lane&31, k=(lane>>5)*8+j
//   C/D: col=lane&31, row=(reg&3)+8*(reg>>2)+4*(lane>>5)
// LDS tiles [64 rows][8 chunks of 16B], chunk slot = c ^ (row&7) (T2,
// via pre-swizzled global source + swizzled reads).
// ---------------------------------------------------------------------------
__global__ __launch_bounds__(512, 4) void attn_kernel(
    const short* __restrict__ Q, const short* __restrict__ K,
    const short* __restrict__ Vt, float* __restrict__ Opart,
    float* __restrict__ Ml, int nspl, int kvlen)
{
    __shared__ __align__(16) short klds[2][64][64];
    __shared__ __align__(16) short vlds[2][64][64];

    const int t    = threadIdx.x;
    const int w    = t >> 6;
    const int l    = t & 63;
    const int l31  = l & 31;
    const int lhi  = l >> 5;
    const int bh   = blockIdx.y;
    const int qtil = blockIdx.x;
    const int spl  = blockIdx.z;
    const int q0   = qtil*QB + w*QW;
    const int kv_beg = spl * kvlen;

    const short* Qh = Q  + (size_t)bh*S_*DH_;
    const short* Kh = K  + (size_t)bh*S_*DH_;
    const short* Vh = Vt + (size_t)bh*DH_*S_;

    // staging: wave w stages rows w*8..w*8+7; source chunk pre-swizzled (T2)
    const int rl  = l >> 3;
    const int cs  = (l & 7) ^ (rl & 7);
    const size_t koff = (size_t)(w*8 + rl)*DH_ + cs*8;
    const size_t voff = (size_t)(w*8 + rl)*S_  + cs*8;
    const int ldst = w*512 + l*8;   // element offset within one 64x64 buffer

    // Q B-frags (per-wave constant): q=q0+l31, dh = k0*16 + lhi*8 + j
    v8s qf[4];
    #pragma unroll
    for (int k0 = 0; k0 < 4; ++k0)
        qf[k0] = *(const v8s*)(Qh + (size_t)(q0 + l31)*DH_ + k0*16 + lhi*8);

    // swizzled frag-read offsets: fo[tile-half][chunkpair]
    int fo[2][4];
    #pragma unroll
    for (int a = 0; a < 2; ++a)
        #pragma unroll
        for (int c = 0; c < 4; ++c)
            fo[a][c] = (a*32 + l31)*64 + (((c*2 + lhi) ^ (l31 & 7))*8);

    v16f o0 = vz16(), o1 = vz16();
    v16f sA0, sA1, sB0, sB1;       // two score sets: even/odd tiles
    float m_run = -INFINITY, l_run = 0.f;
    v8s vhold;                     // V data for the next tile (written top of iter)

    const int NT = kvlen / KVB;    // 16/32/64 -- always even

    auto qkt_into = [&](int buf, v16f& d0, v16f& d1) {
        const short* kb = (const short*)klds + buf*4096;
        d0 = vz16(); d1 = vz16();
        __builtin_amdgcn_s_setprio(1);
        #pragma unroll
        for (int k0 = 0; k0 < 4; ++k0) {
            v8s a0 = *(const v8s*)(kb + fo[0][k0]);
            v8s a1 = *(const v8s*)(kb + fo[1][k0]);
            d0 = __builtin_amdgcn_mfma_f32_32x32x16_bf16(a0, qf[k0], d0, 0, 0, 0);
            d1 = __builtin_amdgcn_mfma_f32_32x32x16_bf16(a1, qf[k0], d1, 0, 0, 0);
        }
        __builtin_amdgcn_s_setprio(0);
    };

    auto smpv_on = [&](int buf, v16f& s0, v16f& s1) {
        const short* vb = (const short*)vlds + buf*4096;

        // online softmax (exp2 domain), max3 tree + defer-max
        float t16[16];
        #pragma unroll
        for (int i = 0; i < 16; ++i) t16[i] = fmaxf(s0[i], s1[i]);
        float r0 = max3f(t16[0],  t16[1],  t16[2]);
        float r1 = max3f(t16[3],  t16[4],  t16[5]);
        float r2 = max3f(t16[6],  t16[7],  t16[8]);
        float r3 = max3f(t16[9],  t16[10], t16[11]);
        float r4 = max3f(t16[12], t16[13], t16[14]);
        float mx = fmaxf(max3f(max3f(r0, r1, r2), r3, r4), t16[15]);
        mx = xmax32(mx);

        if (__any(mx > m_run + DEFER_THR)) {
            float mn = fmaxf(m_run, mx);
            float sc = fexp2(m_run - mn);
            #pragma unroll
            for (int i = 0; i < 16; ++i) { o0[i] *= sc; o1[i] *= sc; }
            l_run *= sc;
            m_run = mn;
        }
        #pragma unroll
        for (int i = 0; i < 16; ++i) s0[i] = fexp2(s0[i] - m_run);
        #pragma unroll
        for (int i = 0; i < 16; ++i) s1[i] = fexp2(s1[i] - m_run);
        float a16[16];
        #pragma unroll
        for (int i = 0; i < 16; ++i) a16[i] = s0[i] + s1[i];
        #pragma unroll
        for (int st = 8; st; st >>= 1)
            #pragma unroll
            for (int i = 0; i < st; ++i) a16[i] += a16[i+st];
        l_run += xadd32(a16[0]);

        // pack P -> 4 PV B-frags (T12)
        unsigned pwv[4][4];
        {
            unsigned j0 = cvtpk(s0[0], s0[1]),  j1 = cvtpk(s0[2], s0[3]);
            unsigned j2 = cvtpk(s0[4], s0[5]),  j3 = cvtpk(s0[6], s0[7]);
            unsigned j4 = cvtpk(s0[8], s0[9]),  j5 = cvtpk(s0[10], s0[11]);
            unsigned j6 = cvtpk(s0[12], s0[13]), j7 = cvtpk(s0[14], s0[15]);
            pl32swap(j0, j2); pl32swap(j1, j3);
            pwv[0][0] = j0; pwv[0][1] = j1; pwv[0][2] = j2; pwv[0][3] = j3;
            pl32swap(j4, j6); pl32swap(j5, j7);
            pwv[1][0] = j4; pwv[1][1] = j5; pwv[1][2] = j6; pwv[1][3] = j7;
        }
        {
            unsigned j0 = cvtpk(s1[0], s1[1]),  j1 = cvtpk(s1[2], s1[3]);
            unsigned j2 = cvtpk(s1[4], s1[5]),  j3 = cvtpk(s1[6], s1[7]);
            unsigned j4 = cvtpk(s1[8], s1[9]),  j5 = cvtpk(s1[10], s1[11]);
            unsigned j6 = cvtpk(s1[12], s1[13]), j7 = cvtpk(s1[14], s1[15]);
            pl32swap(j0, j2); pl32swap(j1, j3);
            pwv[2][0] = j0; pwv[2][1] = j1; pwv[2][2] = j2; pwv[2][3] = j3;
            pl32swap(j4, j6); pl32swap(j5, j7);
            pwv[3][0] = j4; pwv[3][1] = j5; pwv[3][2] = j6; pwv[3][3] = j7;
        }

        // PV: O^T[d][q] += V^T[d][kv] * P^T[kv][q]
        __builtin_amdgcn_s_setprio(1);
        #pragma unroll
        for (int kk = 0; kk < 4; ++kk) {
            v4u u = { pwv[kk][0], pwv[kk][1], pwv[kk][2], pwv[kk][3] };
            v8s pf = __builtin_bit_cast(v8s, u);
            v8s va0 = *(const v8s*)(vb + fo[0][kk]);
            v8s va1 = *(const v8s*)(vb + fo[1][kk]);
            o0 = __builtin_amdgcn_mfma_f32_32x32x16_bf16(va0, pf, o0, 0, 0, 0);
            o1 = __builtin_amdgcn_mfma_f32_32x32x16_bf16(va1, pf, o1, 0, 0, 0);
        }
        __builtin_amdgcn_s_setprio(0);
    };

    // iter body: current tile tc (scores in c0/c1), next tile tc+1 (into n0/n1)
    auto iter_body = [&](int tc, v16f& c0, v16f& c1, v16f& n0, v16f& n1) {
        // V for tile tc+1 (held in regs since last iter) -> vlds[(tc+1)&1].
        // Legal: last read of vlds[(tc+1)&1] was smpv(tc-1), one barrier back.
        if (tc + 1 < NT)
            *(v8s*)((short*)vlds + ((tc+1)&1)*4096 + ldst) = vhold;

        // issue loads for tile tc+2 (T14: a full body to land)
        v8s kn, vn;
        const bool pf = (tc + 2 < NT);
        if (pf) {
            size_t kvn = kv_beg + (size_t)(tc+2)*KVB;
            kn = *(const v8s*)(Kh + kvn*DH_ + koff);
            vn = *(const v8s*)(Vh + kvn + voff);
        }

        // QK^T(tc+1) MFMAs issue first, drain under smpv(tc)'s VALU
        if (tc + 1 < NT) qkt_into((tc+1)&1, n0, n1);
        smpv_on(tc & 1, c0, c1);

        // K for tile tc+2 -> klds[tc&1]. Legal: last read qkt(tc), one
        // barrier back.
        if (pf) {
            *(v8s*)((short*)klds + (tc&1)*4096 + ldst) = kn;
            vhold = vn;
        }
        __syncthreads();
    };

    // prologue: K0->klds0, K1->klds1, V0->vlds0; V1 held in regs
    {
        v8s k0v = *(const v8s*)(Kh + (size_t)kv_beg*DH_ + koff);
        v8s k1v = *(const v8s*)(Kh + ((size_t)kv_beg + KVB)*DH_ + koff);
        v8s v0v = *(const v8s*)(Vh + kv_beg + voff);
        vhold   = *(const v8s*)(Vh + kv_beg + KVB + voff);
        *(v8s*)((short*)klds + ldst)        = k0v;
        *(v8s*)((short*)klds + 4096 + ldst) = k1v;
        *(v8s*)((short*)vlds + ldst)        = v0v;
    }
    __syncthreads();
    qkt_into(0, sA0, sA1);
    __syncthreads();   // protects first kwrite (k2 -> klds0) against laggards

    for (int it = 0; it < NT; it += 2) {
        iter_body(it,     sA0, sA1, sB0, sB1);
        iter_body(it + 1, sB0, sB1, sA0, sA1);
    }

    // --- epilogue: dump unnormalized O^T (reg order) + m/l ---
    const int inst = bh*(S_/QW) + qtil*NW + w;
    float* od = Opart + ((size_t)inst*nspl + spl)*2048;
    #pragma unroll
    for (int r = 0; r < 16; ++r) od[r*64 + l]      = o0[r];
    #pragma unroll
    for (int r = 0; r < 16; ++r) od[(16+r)*64 + l] = o1[r];
    Ml[((size_t)inst*nspl + spl)*64 + l] = (l < 32) ? m_run : l_run;
}

// ---------------------------------------------------------------------------
// Kernel 3: merge KV-split partials, normalize, write fp32 out [B][S][D].
// ---------------------------------------------------------------------------
template<int NSPL>
__global__ __launch_bounds__(256) void combine_kernel(
    const float* __restrict__ Opart, const float* __restrict__ Ml,
    float* __restrict__ out)
{
    const int t = threadIdx.x;
    const int w = t >> 6, l = t & 63;
    const int inst = blockIdx.x*4 + w;
    const int bh = inst >> 7;           // / (S_/QW = 128)
    const int qw = inst & 127;
    const int b = bh >> 2, h = bh & 3;
    const int l31 = l & 31, lhi = l >> 5;
    const int q = qw*32 + l31;

    const float* mlp = Ml + (size_t)inst*NSPL*64;
    float m[NSPL], lv[NSPL];
    float M = -INFINITY;
    #pragma unroll
    for (int sp = 0; sp < NSPL; ++sp) {
        m[sp]  = mlp[sp*64 + l31];
        lv[sp] = mlp[sp*64 + 32 + l31];
        M = fmaxf(M, m[sp]);
    }
    float wgt[NSPL], L = 0.f;
    #pragma unroll
    for (int sp = 0; sp < NSPL; ++sp) {
        wgt[sp] = fexp2(m[sp] - M);
        L += lv[sp] * wgt[sp];
    }
    float inv = 1.f / L;

    const float* op0 = Opart + (size_t)inst*NSPL*2048;
    float* outp = out + ((size_t)(b*S_ + q))*D_ + h*DH_;

    #pragma unroll
    for (int g = 0; g < 8; ++g) {
        v4f acc;
        #pragma unroll
        for (int jj = 0; jj < 4; ++jj) {
            int r = g*4 + jj;
            float v = 0.f;
            #pragma unroll
            for (int sp = 0; sp < NSPL; ++sp)
                v += op0[sp*2048 + r*64 + l] * wgt[sp];
            acc[jj] = v * inv;
        }
        int td = g >> 2, gg = g & 3;
        int d = td*32 + gg*8 + lhi*4;
        *(v4f*)(outp + d) = acc;
    }
}

extern "C" void kernel_launch(void* const* d_in, const int* in_sizes, int n_in,
                              void* d_out, int out_size, void* d_ws, size_t ws_size,
                              hipStream_t stream)
{
    const float* x  = (const float*)d_in[0];
    const float* qw = (const float*)d_in[1];
    const float* qb = (const float*)d_in[2];
    const float* kw = (const float*)d_in[3];
    const float* kb = (const float*)d_in[4];
    const float* vw = (const float*)d_in[5];
    const float* vb = (const float*)d_in[6];

    short* Qb  = (short*)d_ws;
    short* Kb  = Qb + NTOK;
    short* Vtb = Kb + NTOK;
    float* Opart = (float*)(Vtb + NTOK);

    // KV-split: 4 (2 blocks/CU; beyond that LDS BW saturates -- R6 evidence)
    size_t base = (size_t)3*NTOK*sizeof(short);
    size_t per_spl = (size_t)NINST*2048*4 + (size_t)NINST*64*4;
    int nspl = 1;
    if      (ws_size >= base + 4*per_spl) nspl = 4;
    else if (ws_size >= base + 2*per_spl) nspl = 2;
    float* Ml = Opart + (size_t)NINST*nspl*2048;
    int kvlen = S_/nspl;

    float* out = (float*)d_out;

    dim3 pg(S_/32, BH_), pb(128);
    hipLaunchKernelGGL(qkv_proj_mfma, pg, pb, 0, stream,
                       x, qw, qb, kw, kb, vw, vb, Qb, Kb, Vtb);

    dim3 ag(S_/QB, BH_, nspl), ab(512);
    hipLaunchKernelGGL(attn_kernel, ag, ab, 0, stream, Qb, Kb, Vtb, Opart, Ml, nspl, kvlen);

    dim3 cg(NINST/4), cb(256);
    if (nspl == 4)
        hipLaunchKernelGGL(combine_kernel<4>, cg, cb, 0, stream, Opart, Ml, out);
    else if (nspl == 2)
        hipLaunchKernelGGL(combine_kernel<2>, cg, cb, 0, stream, Opart, Ml, out);
    else
        hipLaunchKernelGGL(combine_kernel<1>, cg, cb, 0, stream, Opart, Ml, out);
}

// Round 10
// 73.987 us; speedup vs baseline: 2.0220x; 2.0220x over previous
//
#include <hip/hip_runtime.h>
#include <hip/hip_bf16.h>

// MSA: B=2, S=4096, D=256, H=4, DH=64. fp32 in/out, bf16 MFMA internally.
// R10: QW=64 (each wave computes 64 q-rows) -- halves LDS-read traffic per
//      unit work. R9 diagnosis: R4's 54.7us attn is LDS-BW-bound (16 waves
//      x 16KB reads = 256KB/CU-round = 2048cyc = measured round time).
//      4 waves x 256 thr/block, launch_bounds(256,2) for the 256-reg budget
//      (R9 lesson: (512,4) = 128-reg cap caused the scratch-spill blowup).
//      Skeleton otherwise identical to R4 (2 LDS buffers, 1 barrier/tile,
//      reg staging, T2 swizzle, defer-max, permlane pack, MFMA proj).

#define B_   2
#define S_   4096
#define D_   256
#define H_   4
#define DH_  64
#define BH_  8
#define NTOK (BH_*S_*DH_)    // elements per Q/K/V buffer

#define KVB  64              // kv tile per step
#define QW   64              // q rows per wave (was 32)
#define NW   4               // waves per block
#define QB   (QW*NW)         // 256 q rows per block
#define QWI  32              // q-instance width (combine-kernel granularity)
#define NINST (BH_*(S_/QWI)) // 1024 q-instances

typedef short v8s __attribute__((ext_vector_type(8)));
typedef float v16f __attribute__((ext_vector_type(16)));
typedef float v4f __attribute__((ext_vector_type(4)));
typedef unsigned v4u __attribute__((ext_vector_type(4)));
typedef unsigned v2u __attribute__((ext_vector_type(2)));
typedef int v2i __attribute__((ext_vector_type(2)));

#define QSCL (0.125f * 1.4426950408889634f)   // 1/sqrt(64) * log2(e)
#define DEFER_THR 8.0f                        // T13

static __device__ __forceinline__ short f2bf(float f) {
    __hip_bfloat16 h = __float2bfloat16(f);
    return *reinterpret_cast<short*>(&h);
}
static __device__ __forceinline__ unsigned cvtpk(float lo, float hi) {
    unsigned r;
    asm("v_cvt_pk_bf16_f32 %0, %1, %2" : "=v"(r) : "v"(lo), "v"(hi));
    return r;
}
static __device__ __forceinline__ float fexp2(float x) {
#if __has_builtin(__builtin_amdgcn_exp2f)
    return __builtin_amdgcn_exp2f(x);
#else
    float r;
    asm("v_exp_f32 %0, %1" : "=v"(r) : "v"(x));
    return r;
#endif
}
static __device__ __forceinline__ float max3f(float a, float b, float c) {
    return fmaxf(fmaxf(a, b), c);
}
static __device__ __forceinline__ void pl32swap(unsigned &a, unsigned &b) {
#if __has_builtin(__builtin_amdgcn_permlane32_swap)
    v2i r = __builtin_amdgcn_permlane32_swap((int)a, (int)b, false, false);
    a = (unsigned)r[0]; b = (unsigned)r[1];
#else
    asm volatile("v_permlane32_swap_b32 %0, %1" : "+v"(a), "+v"(b));
#endif
}
static __device__ __forceinline__ float xmax32(float x) {
    unsigned a = __builtin_bit_cast(unsigned, x), b = a;
    pl32swap(a, b);
    return fmaxf(__builtin_bit_cast(float, a), __builtin_bit_cast(float, b));
}
static __device__ __forceinline__ float xadd32(float x) {
    unsigned a = __builtin_bit_cast(unsigned, x), b = a;
    pl32swap(a, b);
    return __builtin_bit_cast(float, a) + __builtin_bit_cast(float, b);
}
static __device__ __forceinline__ v16f vz16() {
    v16f z;
    #pragma unroll
    for (int i = 0; i < 16; ++i) z[i] = 0.f;
    return z;
}
static __device__ __forceinline__ v8s cvt8(const float* p) {
    v4f f0 = *(const v4f*)(p);
    v4f f1 = *(const v4f*)(p + 4);
    v4u u = { cvtpk(f0[0], f0[1]), cvtpk(f0[2], f0[3]),
              cvtpk(f1[0], f1[1]), cvtpk(f1[2], f1[3]) };
    return __builtin_bit_cast(v8s, u);
}

// ---------------------------------------------------------------------------
// Kernel 1: MFMA QKV projection (unchanged from R5).
//   Q: [BH][S][DH] pre-scaled by QSCL; K: [BH][S][DH]; Vt: [BH][DH][S].
// ---------------------------------------------------------------------------
__global__ __launch_bounds__(128) void qkv_proj_mfma(
    const float* __restrict__ x,
    const float* __restrict__ qw, const float* __restrict__ qb,
    const float* __restrict__ kw, const float* __restrict__ kb,
    const float* __restrict__ vw, const float* __restrict__ vb,
    short* __restrict__ Qo, short* __restrict__ Ko, short* __restrict__ Vt)
{
    const int t   = threadIdx.x;
    const int w   = t >> 6;
    const int l   = t & 63;
    const int l31 = l & 31, lhi = l >> 5;
    const int bh  = blockIdx.y, h = bh & 3, b = bh >> 2;
    const int s0  = blockIdx.x * 32;

    const float* xrow = x + ((size_t)(b*S_ + s0 + l31))*D_ + h*DH_;
    v8s af[4];
    #pragma unroll
    for (int k0 = 0; k0 < 4; ++k0)
        af[k0] = cvt8(xrow + k0*16 + lhi*8);

    const float* Wp[3] = { qw + h*DH_*DH_, kw + h*DH_*DH_, vw + h*DH_*DH_ };
    const float* Bp[3] = { qb + h*DH_,     kb + h*DH_,     vb + h*DH_ };
    short* Qh = Qo + (size_t)bh*S_*DH_;
    short* Kh = Ko + (size_t)bh*S_*DH_;

    #pragma unroll
    for (int ui = 0; ui < 3; ++ui) {
        const int u  = w*3 + ui;
        const int p  = u >> 1;
        const int eb = u & 1;
        const int e  = eb*32 + l31;
        const float* wrow = Wp[p] + e*DH_;

        v16f acc = vz16();
        #pragma unroll
        for (int k0 = 0; k0 < 4; ++k0) {
            v8s bfr = cvt8(wrow + k0*16 + lhi*8);
            acc = __builtin_amdgcn_mfma_f32_32x32x16_bf16(af[k0], bfr, acc, 0, 0, 0);
        }

        const float bias = Bp[p][e];
        if (p == 0) {
            const float bq = bias * QSCL;
            #pragma unroll
            for (int r = 0; r < 16; ++r) acc[r] = fmaf(acc[r], QSCL, bq);
        } else {
            #pragma unroll
            for (int r = 0; r < 16; ++r) acc[r] += bias;
        }

        if (p < 2) {
            short* dst = (p == 0) ? Qh : Kh;
            #pragma unroll
            for (int r = 0; r < 16; ++r) {
                int s = s0 + (r & 3) + 8*(r >> 2) + 4*lhi;
                dst[(size_t)s*DH_ + e] = f2bf(acc[r]);
            }
        } else {
            short* vtb = Vt + (size_t)bh*DH_*S_ + (size_t)e*S_;
            #pragma unroll
            for (int rq = 0; rq < 4; ++rq) {
                v2u pr = { cvtpk(acc[rq*4+0], acc[rq*4+1]),
                           cvtpk(acc[rq*4+2], acc[rq*4+3]) };
                int s = s0 + rq*8 + 4*lhi;
                *(v2u*)(vtb + s) = pr;
            }
        }
    }
}

// ---------------------------------------------------------------------------
// Kernel 2: flash attention, QW=64 per wave, swapped QK^T, 32x32x16 MFMA.
// Fragment layouts (m74/m101):
//   A: row=lane&31, k=(lane>>5)*8+j ; B: col=lane&31, k=(lane>>5)*8+j
//   C/D: col=lane&31, row=(reg&3)+8*(reg>>2)+4*(lane>>5)
// LDS tiles [64 rows][8 chunks of 16B], phys chunk = logical ^ (row&7) (T2);
// staging: 256 threads x 2 chunk-pairs, pre-swizzled global source.
// ---------------------------------------------------------------------------
__global__ __launch_bounds__(256, 2) void attn_kernel(
    const short* __restrict__ Q, const short* __restrict__ K,
    const short* __restrict__ Vt, float* __restrict__ Opart,
    float* __restrict__ Ml, int nspl, int kvlen)
{
    __shared__ __align__(16) short klds[2][64][64];
    __shared__ __align__(16) short vlds[2][64][64];

    const int t    = threadIdx.x;
    const int w    = t >> 6;
    const int l    = t & 63;
    const int l31  = l & 31;
    const int lhi  = l >> 5;
    const int bh   = blockIdx.y;
    const int qtil = blockIdx.x;
    const int spl  = blockIdx.z;
    const int q0   = qtil*QB + w*QW;
    const int kv_beg = spl * kvlen;

    const short* Qh = Q  + (size_t)bh*S_*DH_;
    const short* Kh = K  + (size_t)bh*S_*DH_;
    const short* Vh = Vt + (size_t)bh*DH_*S_;

    // staging geometry: thread t covers tile row srow = t>>2, phys chunks
    // p0, p0+1 where p0 = (t&3)*2; global source chunks pre-swizzled.
    const int srow = t >> 2;
    const int p0   = (t & 3) * 2;
    const int r7   = srow & 7;
    const int sc0  = p0 ^ r7;
    const int sc1  = (p0 + 1) ^ r7;
    const size_t koff0 = (size_t)srow*DH_ + sc0*8;
    const size_t koff1 = (size_t)srow*DH_ + sc1*8;
    const size_t voff0 = (size_t)srow*S_  + sc0*8;
    const size_t voff1 = (size_t)srow*S_  + sc1*8;
    const int d0 = srow*64 + p0*8;    // linear dest (elements) in a buffer

    // Q B-frags for both q-halves: q = q0 + b*32 + l31, k = k0*16 + lhi*8 + j
    v8s qf[2][4];
    #pragma unroll
    for (int b = 0; b < 2; ++b)
        #pragma unroll
        for (int k0 = 0; k0 < 4; ++k0)
            qf[b][k0] = *(const v8s*)(Qh + (size_t)(q0 + b*32 + l31)*DH_ + k0*16 + lhi*8);

    // swizzled frag-read offsets: fo[row-half a][chunk-pair c]
    int fo[2][4];
    #pragma unroll
    for (int a = 0; a < 2; ++a)
        #pragma unroll
        for (int c = 0; c < 4; ++c)
            fo[a][c] = (a*32 + l31)*64 + (((c*2 + lhi) ^ (l31 & 7))*8);

    v16f o0 = vz16(), o1 = vz16(), o2 = vz16(), o3 = vz16();
    float m0 = -INFINITY, l0 = 0.f, m1 = -INFINITY, l1 = 0.f;

    const int NT = kvlen / KVB;

    // row-max of a score group (one q-half): 32 values per lane-pair
    auto rowmax = [&](const v16f& a, const v16f& b) -> float {
        float t16[16];
        #pragma unroll
        for (int i = 0; i < 16; ++i) t16[i] = fmaxf(a[i], b[i]);
        float r0 = max3f(t16[0],  t16[1],  t16[2]);
        float r1 = max3f(t16[3],  t16[4],  t16[5]);
        float r2 = max3f(t16[6],  t16[7],  t16[8]);
        float r3 = max3f(t16[9],  t16[10], t16[11]);
        float r4 = max3f(t16[12], t16[13], t16[14]);
        float mx = fmaxf(max3f(max3f(r0, r1, r2), r3, r4), t16[15]);
        return xmax32(mx);
    };

    // exp2 in place, accumulate row-sum into lr, pack into pw[4][4]
    auto finish = [&](v16f& a, v16f& b, float m, float& lr, unsigned (&pw)[4][4]) {
        #pragma unroll
        for (int i = 0; i < 16; ++i) a[i] = fexp2(a[i] - m);
        #pragma unroll
        for (int i = 0; i < 16; ++i) b[i] = fexp2(b[i] - m);
        float a16[16];
        #pragma unroll
        for (int i = 0; i < 16; ++i) a16[i] = a[i] + b[i];
        #pragma unroll
        for (int st = 8; st; st >>= 1)
            #pragma unroll
            for (int i = 0; i < st; ++i) a16[i] += a16[i+st];
        lr += xadd32(a16[0]);

        {
            unsigned j0 = cvtpk(a[0], a[1]),   j1 = cvtpk(a[2], a[3]);
            unsigned j2 = cvtpk(a[4], a[5]),   j3 = cvtpk(a[6], a[7]);
            unsigned j4 = cvtpk(a[8], a[9]),   j5 = cvtpk(a[10], a[11]);
            unsigned j6 = cvtpk(a[12], a[13]), j7 = cvtpk(a[14], a[15]);
            pl32swap(j0, j2); pl32swap(j1, j3);
            pw[0][0] = j0; pw[0][1] = j1; pw[0][2] = j2; pw[0][3] = j3;
            pl32swap(j4, j6); pl32swap(j5, j7);
            pw[1][0] = j4; pw[1][1] = j5; pw[1][2] = j6; pw[1][3] = j7;
        }
        {
            unsigned j0 = cvtpk(b[0], b[1]),   j1 = cvtpk(b[2], b[3]);
            unsigned j2 = cvtpk(b[4], b[5]),   j3 = cvtpk(b[6], b[7]);
            unsigned j4 = cvtpk(b[8], b[9]),   j5 = cvtpk(b[10], b[11]);
            unsigned j6 = cvtpk(b[12], b[13]), j7 = cvtpk(b[14], b[15]);
            pl32swap(j0, j2); pl32swap(j1, j3);
            pw[2][0] = j0; pw[2][1] = j1; pw[2][2] = j2; pw[2][3] = j3;
            pl32swap(j4, j6); pl32swap(j5, j7);
            pw[3][0] = j4; pw[3][1] = j5; pw[3][2] = j6; pw[3][3] = j7;
        }
    };

    // prologue: stage tile 0 -> buf 0
    {
        size_t kv0 = (size_t)kv_beg;
        v8s ka = *(const v8s*)(Kh + kv0*DH_ + koff0);
        v8s kb2 = *(const v8s*)(Kh + kv0*DH_ + koff1);
        v8s va = *(const v8s*)(Vh + kv0 + voff0);
        v8s vb2 = *(const v8s*)(Vh + kv0 + voff1);
        *(v8s*)((short*)klds + d0)     = ka;
        *(v8s*)((short*)klds + d0 + 8) = kb2;
        *(v8s*)((short*)vlds + d0)     = va;
        *(v8s*)((short*)vlds + d0 + 8) = vb2;
    }
    __syncthreads();

    for (int it = 0; it < NT; ++it) {
        const int cur = it & 1;

        // T14: issue next tile's loads; they land during this body
        v8s ka, kb2, va, vb2;
        const bool pf = (it + 1 < NT);
        if (pf) {
            size_t kvn = kv_beg + (size_t)(it+1)*KVB;
            ka  = *(const v8s*)(Kh + kvn*DH_ + koff0);
            kb2 = *(const v8s*)(Kh + kvn*DH_ + koff1);
            va  = *(const v8s*)(Vh + kvn + voff0);
            vb2 = *(const v8s*)(Vh + kvn + voff1);
        }

        const short* kb = (const short*)klds + cur*4096;
        const short* vb = (const short*)vlds + cur*4096;

        // --- QK^T: S^T[kv][q] for both q-halves; K frags shared ---
        v16f s0 = vz16(), s1 = vz16(), s2 = vz16(), s3 = vz16();
        __builtin_amdgcn_s_setprio(1);
        #pragma unroll
        for (int k0 = 0; k0 < 4; ++k0) {
            v8s a0 = *(const v8s*)(kb + fo[0][k0]);
            v8s a1 = *(const v8s*)(kb + fo[1][k0]);
            s0 = __builtin_amdgcn_mfma_f32_32x32x16_bf16(a0, qf[0][k0], s0, 0, 0, 0);
            s1 = __builtin_amdgcn_mfma_f32_32x32x16_bf16(a1, qf[0][k0], s1, 0, 0, 0);
            s2 = __builtin_amdgcn_mfma_f32_32x32x16_bf16(a0, qf[1][k0], s2, 0, 0, 0);
            s3 = __builtin_amdgcn_mfma_f32_32x32x16_bf16(a1, qf[1][k0], s3, 0, 0, 0);
        }
        __builtin_amdgcn_s_setprio(0);

        // --- online softmax (both q-halves) with shared defer branch ---
        float mx0 = rowmax(s0, s1);
        float mx1 = rowmax(s2, s3);
        if (__any(fmaxf(mx0 - m0, mx1 - m1) > DEFER_THR)) {
            float mn0 = fmaxf(m0, mx0), mn1 = fmaxf(m1, mx1);
            float sc0f = fexp2(m0 - mn0), sc1f = fexp2(m1 - mn1);
            #pragma unroll
            for (int i = 0; i < 16; ++i) { o0[i] *= sc0f; o1[i] *= sc0f; }
            #pragma unroll
            for (int i = 0; i < 16; ++i) { o2[i] *= sc1f; o3[i] *= sc1f; }
            l0 *= sc0f; l1 *= sc1f;
            m0 = mn0; m1 = mn1;
        }
        unsigned pw0[4][4], pw1[4][4];
        finish(s0, s1, m0, l0, pw0);
        finish(s2, s3, m1, l1, pw1);

        // --- PV: O^T[d][q] += V^T[d][kv] * P^T[kv][q]; V frags shared ---
        __builtin_amdgcn_s_setprio(1);
        #pragma unroll
        for (int kk = 0; kk < 4; ++kk) {
            v4u u0 = { pw0[kk][0], pw0[kk][1], pw0[kk][2], pw0[kk][3] };
            v4u u1 = { pw1[kk][0], pw1[kk][1], pw1[kk][2], pw1[kk][3] };
            v8s pf0 = __builtin_bit_cast(v8s, u0);
            v8s pf1 = __builtin_bit_cast(v8s, u1);
            v8s va0 = *(const v8s*)(vb + fo[0][kk]);
            v8s va1 = *(const v8s*)(vb + fo[1][kk]);
            o0 = __builtin_amdgcn_mfma_f32_32x32x16_bf16(va0, pf0, o0, 0, 0, 0);
            o1 = __builtin_amdgcn_mfma_f32_32x32x16_bf16(va1, pf0, o1, 0, 0, 0);
            o2 = __builtin_amdgcn_mfma_f32_32x32x16_bf16(va0, pf1, o2, 0, 0, 0);
            o3 = __builtin_amdgcn_mfma_f32_32x32x16_bf16(va1, pf1, o3, 0, 0, 0);
        }
        __builtin_amdgcn_s_setprio(0);

        // stage next tile into the other buffer (one barrier after its
        // last read at iter it-1)
        if (pf) {
            short* kd = (short*)klds + (cur^1)*4096;
            short* vd = (short*)vlds + (cur^1)*4096;
            *(v8s*)(kd + d0)     = ka;
            *(v8s*)(kd + d0 + 8) = kb2;
            *(v8s*)(vd + d0)     = va;
            *(v8s*)(vd + d0 + 8) = vb2;
        }
        __syncthreads();
    }

    // --- epilogue: two 32-q instances per wave ---
    const int instb = bh*(S_/QWI) + qtil*(QB/QWI) + w*2;
    {
        float* od = Opart + ((size_t)instb*nspl + spl)*2048;
        #pragma unroll
        for (int r = 0; r < 16; ++r) od[r*64 + l]      = o0[r];
        #pragma unroll
        for (int r = 0; r < 16; ++r) od[(16+r)*64 + l] = o1[r];
        Ml[((size_t)instb*nspl + spl)*64 + l] = (l < 32) ? m0 : l0;
    }
    {
        const int inst = instb + 1;
        float* od = Opart + ((size_t)inst*nspl + spl)*2048;
        #pragma unroll
        for (int r = 0; r < 16; ++r) od[r*64 + l]      = o2[r];
        #pragma unroll
        for (int r = 0; r < 16; ++r) od[(16+r)*64 + l] = o3[r];
        Ml[((size_t)inst*nspl + spl)*64 + l] = (l < 32) ? m1 : l1;
    }
}

// ---------------------------------------------------------------------------
// Kernel 3: merge KV-split partials, normalize, write fp32 out [B][S][D].
// ---------------------------------------------------------------------------
template<int NSPL>
__global__ __launch_bounds__(256) void combine_kernel(
    const float* __restrict__ Opart, const float* __restrict__ Ml,
    float* __restrict__ out)
{
    const int t = threadIdx.x;
    const int w = t >> 6, l = t & 63;
    const int inst = blockIdx.x*4 + w;
    const int bh = inst >> 7;
    const int qw = inst & 127;
    const int b = bh >> 2, h = bh & 3;
    const int l31 = l & 31, lhi = l >> 5;
    const int q = qw*32 + l31;

    const float* mlp = Ml + (size_t)inst*NSPL*64;
    float m[NSPL], lv[NSPL];
    float M = -INFINITY;
    #pragma unroll
    for (int sp = 0; sp < NSPL; ++sp) {
        m[sp]  = mlp[sp*64 + l31];
        lv[sp] = mlp[sp*64 + 32 + l31];
        M = fmaxf(M, m[sp]);
    }
    float wgt[NSPL], L = 0.f;
    #pragma unroll
    for (int sp = 0; sp < NSPL; ++sp) {
        wgt[sp] = fexp2(m[sp] - M);
        L += lv[sp] * wgt[sp];
    }
    float inv = 1.f / L;

    const float* op0 = Opart + (size_t)inst*NSPL*2048;
    float* outp = out + ((size_t)(b*S_ + q))*D_ + h*DH_;

    #pragma unroll
    for (int g = 0; g < 8; ++g) {
        v4f acc;
        #pragma unroll
        for (int jj = 0; jj < 4; ++jj) {
            int r = g*4 + jj;
            float v = 0.f;
            #pragma unroll
            for (int sp = 0; sp < NSPL; ++sp)
                v += op0[sp*2048 + r*64 + l] * wgt[sp];
            acc[jj] = v * inv;
        }
        int td = g >> 2, gg = g & 3;
        int d = td*32 + gg*8 + lhi*4;
        *(v4f*)(outp + d) = acc;
    }
}

extern "C" void kernel_launch(void* const* d_in, const int* in_sizes, int n_in,
                              void* d_out, int out_size, void* d_ws, size_t ws_size,
                              hipStream_t stream)
{
    const float* x  = (const float*)d_in[0];
    const float* qw = (const float*)d_in[1];
    const float* qb = (const float*)d_in[2];
    const float* kw = (const float*)d_in[3];
    const float* kb = (const float*)d_in[4];
    const float* vw = (const float*)d_in[5];
    const float* vb = (const float*)d_in[6];

    short* Qb  = (short*)d_ws;
    short* Kb  = Qb + NTOK;
    short* Vtb = Kb + NTOK;
    float* Opart = (float*)(Vtb + NTOK);

    size_t base = (size_t)3*NTOK*sizeof(short);
    size_t per_spl = (size_t)NINST*2048*4 + (size_t)NINST*64*4;
    int nspl = 1;
    if      (ws_size >= base + 4*per_spl) nspl = 4;
    else if (ws_size >= base + 2*per_spl) nspl = 2;
    float* Ml = Opart + (size_t)NINST*nspl*2048;
    int kvlen = S_/nspl;

    float* out = (float*)d_out;

    dim3 pg(S_/32, BH_), pb(128);
    hipLaunchKernelGGL(qkv_proj_mfma, pg, pb, 0, stream,
                       x, qw, qb, kw, kb, vw, vb, Qb, Kb, Vtb);

    dim3 ag(S_/QB, BH_, nspl), ab(256);
    hipLaunchKernelGGL(attn_kernel, ag, ab, 0, stream, Qb, Kb, Vtb, Opart, Ml, nspl, kvlen);

    dim3 cg(NINST/4), cb(256);
    if (nspl == 4)
        hipLaunchKernelGGL(combine_kernel<4>, cg, cb, 0, stream, Opart, Ml, out);
    else if (nspl == 2)
        hipLaunchKernelGGL(combine_kernel<2>, cg, cb, 0, stream, Opart, Ml, out);
    else
        hipLaunchKernelGGL(combine_kernel<1>, cg, cb, 0, stream, Opart, Ml, out);
}